// Round 5
// baseline (359.227 us; speedup 1.0000x reference)
//
#include <hip/hip_runtime.h>
#include <hip/hip_bf16.h>
#include <math.h>

// LGCN layer, CSR-bucketed (no f32 atomics):
//   agg = segsum(atten*src) @ W_rel          (W_rel commutes out of the sum)
//   att_logit = s1[src] + s2[dst]            (lin_w splits into two per-node dots)
// Pipeline: precompute s1/s2 (+zero offs) -> dst histogram -> 3-stage scan ->
//           scatter (src,att) into dst buckets -> wave-per-8-node gather-reduce
//           fused with W_rel/loop matvecs + tanh epilogue.
// R4: reduce_finalize was latency-bound (VALUBusy 22%, serial offs->ebuf->feat
//     chain per node) -> contiguous 8-node ranges per wave, 9 bucket bounds in
//     one vector load + readlane, gather unroll 16; hist/scatter now 4 edges
//     per thread (int4) for 4 independent memory chains per thread.

#define D 64
#define SCAN_BLOCKS 256
#define SCAN_TPB 256
#define NPW 8   // nodes per wave in reduce_finalize

// ---------------- kernel 1: per-node attention scalars + zero offs ----------
__global__ __launch_bounds__(256) void precompute_att(
    const float* __restrict__ feat, const float* __restrict__ lin_w,
    const float* __restrict__ lin_b, float* __restrict__ s1,
    float* __restrict__ s2, int* __restrict__ offs, int N) {
  const int gt = blockIdx.x * 256 + threadIdx.x;
  for (int i = gt; i < N; i += gridDim.x * 256) offs[i] = 0;

  const int lane = threadIdx.x & 63;
  const int wid  = (blockIdx.x * blockDim.x + threadIdx.x) >> 6;
  const int nw   = (gridDim.x * blockDim.x) >> 6;
  const float w1 = lin_w[lane];
  const float w2 = lin_w[64 + lane];
  const float b  = lin_b[0];
  for (int i = wid; i < N; i += nw) {
    const float f = feat[(size_t)i * D + lane];
    float v1 = f * w1;
    float v2 = f * w2;
    #pragma unroll
    for (int off = 32; off > 0; off >>= 1) {
      v1 += __shfl_down(v1, off, 64);
      v2 += __shfl_down(v2, off, 64);
    }
    if (lane == 0) {
      s1[i] = v1 + b;   // fold bias into s1
      s2[i] = v2;
    }
  }
}

// ---------------- kernel 2: dst histogram, 4 edges/thread ----------------
__global__ __launch_bounds__(256) void hist_dst(
    const int4* __restrict__ edst4, int* __restrict__ offs, int E4) {
  const int t = blockIdx.x * 256 + threadIdx.x;
  if (t >= E4) return;
  const int4 d = edst4[t];
  atomicAdd(&offs[d.x], 1);
  atomicAdd(&offs[d.y], 1);
  atomicAdd(&offs[d.z], 1);
  atomicAdd(&offs[d.w], 1);
}

// ---------------- scan stage A: per-chunk partial sums ----------------
__global__ __launch_bounds__(SCAN_TPB) void scan_partials(
    const int* __restrict__ data, int* __restrict__ partials, int N, int ipb) {
  __shared__ int red[SCAN_TPB / 64];
  const int b = blockIdx.x * ipb;
  const int e = min(b + ipb, N);
  int sum = 0;
  for (int i = b + threadIdx.x; i < e; i += SCAN_TPB) sum += data[i];
  #pragma unroll
  for (int off = 32; off > 0; off >>= 1) sum += __shfl_down(sum, off, 64);
  if ((threadIdx.x & 63) == 0) red[threadIdx.x >> 6] = sum;
  __syncthreads();
  if (threadIdx.x == 0) {
    int t = 0;
    #pragma unroll
    for (int w = 0; w < SCAN_TPB / 64; ++w) t += red[w];
    partials[blockIdx.x] = t;
  }
}

// ---------------- scan stage B: exclusive-scan the 256 partials ----------------
__global__ __launch_bounds__(SCAN_BLOCKS) void scan_level2(
    int* __restrict__ partials) {
  __shared__ int tot[SCAN_BLOCKS];
  const int t = threadIdx.x;
  int v = partials[t];
  tot[t] = v;
  __syncthreads();
  for (int off = 1; off < SCAN_BLOCKS; off <<= 1) {
    int u = tot[t] + ((t >= off) ? tot[t - off] : 0);
    __syncthreads();
    tot[t] = u;
    __syncthreads();
  }
  partials[t] = tot[t] - v;   // exclusive
}

// ---------------- scan stage C: parallel in-chunk exclusive scan + base ------
// requires ipb <= SCAN_TPB (N=50000 -> ipb=196)
__global__ __launch_bounds__(SCAN_TPB) void scan_chunks(
    int* __restrict__ data, const int* __restrict__ partials, int N, int ipb) {
  __shared__ int tot[SCAN_TPB];
  const int t = threadIdx.x;
  const int b = blockIdx.x * ipb;
  const int i = b + t;
  const int v = (t < ipb && i < N) ? data[i] : 0;
  tot[t] = v;
  __syncthreads();
  for (int off = 1; off < SCAN_TPB; off <<= 1) {
    int u = tot[t] + ((t >= off) ? tot[t - off] : 0);
    __syncthreads();
    tot[t] = u;
    __syncthreads();
  }
  if (t < ipb && i < N) data[i] = tot[t] - v + partials[blockIdx.x];
}

// ---------------- kernel 4: scatter (src, att), 4 edges/thread --------------
// Consumes offs via atomicAdd; afterwards offs[n] == bucket END of node n,
// bucket BEGIN of node n == offs[n-1] (0 for n==0).
__global__ __launch_bounds__(256) void scatter_att(
    const int4* __restrict__ esrc4, const int4* __restrict__ edst4,
    const float* __restrict__ s1, const float* __restrict__ s2,
    int* __restrict__ offs, uint2* __restrict__ ebuf, int E4) {
  const int t = blockIdx.x * 256 + threadIdx.x;
  if (t >= E4) return;
  const int4 s = esrc4[t];
  const int4 d = edst4[t];
  const int srcs[4] = {s.x, s.y, s.z, s.w};
  const int dsts[4] = {d.x, d.y, d.z, d.w};
  float a1[4], a2[4];
  #pragma unroll
  for (int j = 0; j < 4; ++j) a1[j] = s1[srcs[j]];   // 4 independent gathers
  #pragma unroll
  for (int j = 0; j < 4; ++j) a2[j] = s2[dsts[j]];
  #pragma unroll
  for (int j = 0; j < 4; ++j) {
    const float a = 1.0f / (1.0f + __expf(-fmaxf(a1[j] + a2[j], 0.0f)));
    const int pos = atomicAdd(&offs[dsts[j]], 1);
    ebuf[pos] = make_uint2((unsigned)srcs[j], __float_as_uint(a));
  }
}

// ---------------- kernel 5: fused gather-reduce + finalize ----------------
// Wave handles NPW consecutive nodes; all NPW+1 bucket bounds loaded in one
// vector load (lane i -> offs[n0-1+i]) and read back via readlane.
__global__ __launch_bounds__(256) void reduce_finalize(
    const float* __restrict__ feat, const float* __restrict__ norm,
    const int* __restrict__ offs, const uint2* __restrict__ ebuf,
    const float* __restrict__ W_rel, const float* __restrict__ loop_w,
    const float* __restrict__ evolve_w, float* __restrict__ out, int N) {
  const int lane = threadIdx.x & 63;
  const int wid  = blockIdx.x * 4 + (threadIdx.x >> 6);
  const int n0   = wid * NPW;
  if (n0 >= N) return;
  const int jmax = min(NPW, N - n0);

  // batched bucket bounds: lane i in [0, NPW] holds offs[n0-1+i] (0 if n0==0,i==0)
  int off_v = 0;
  const int oidx = n0 - 1 + lane;
  if (lane <= NPW && oidx >= 0 && oidx < N) off_v = offs[oidx];

  for (int j = 0; j < jmax; ++j) {
    const int n   = n0 + j;
    const int beg = __builtin_amdgcn_readlane(off_v, j);
    const int end = __builtin_amdgcn_readlane(off_v, j + 1);
    const float f  = feat[(size_t)n * D + lane];
    const float nr = norm[n];

    float agg = 0.0f;
    int p = beg;
    for (; p + 16 <= end; p += 16) {   // 16 independent 256B gathers in flight
      uint2 ee[16];
      #pragma unroll
      for (int q = 0; q < 16; ++q) ee[q] = ebuf[p + q];
      float ff[16];
      #pragma unroll
      for (int q = 0; q < 16; ++q) ff[q] = feat[(size_t)ee[q].x * D + lane];
      #pragma unroll
      for (int q = 0; q < 16; ++q) agg += __uint_as_float(ee[q].y) * ff[q];
    }
    for (; p + 4 <= end; p += 4) {
      uint2 ee[4];
      #pragma unroll
      for (int q = 0; q < 4; ++q) ee[q] = ebuf[p + q];
      #pragma unroll
      for (int q = 0; q < 4; ++q)
        agg += __uint_as_float(ee[q].y) * feat[(size_t)ee[q].x * D + lane];
    }
    for (; p < end; ++p) {
      const uint2 en = ebuf[p];
      agg += __uint_as_float(en.y) * feat[(size_t)en.x * D + lane];
    }

    const bool hm = end > beg;   // wave-uniform branch
    float nf, lm = 0.0f;
    if (hm) {
      float a1 = 0.0f;
      #pragma unroll 8
      for (int k = 0; k < D; ++k) {
        const float fb = __shfl(f, k, 64);
        const float pb = __shfl(agg, k, 64);
        a1 += pb * W_rel[k * D + lane];
        lm += fb * loop_w[k * D + lane];
      }
      nf = a1 * nr;
    } else {
      #pragma unroll 8
      for (int k = 0; k < D; ++k) {
        const float fb = __shfl(f, k, 64);
        lm += fb * evolve_w[k * D + lane];
      }
      nf = f * nr;   // zero in-degree keeps old feat
    }
    out[(size_t)n * D + lane] = tanhf(nf + lm);
  }
}

extern "C" void kernel_launch(void* const* d_in, const int* in_sizes, int n_in,
                              void* d_out, int out_size, void* d_ws, size_t ws_size,
                              hipStream_t stream) {
  const float* feat     = (const float*)d_in[0];
  const float* norm     = (const float*)d_in[1];
  const int*   esrc     = (const int*)d_in[2];
  const int*   edst     = (const int*)d_in[3];
  // d_in[4] = etype: no-op permutation per the reference
  const float* W_rel    = (const float*)d_in[5];
  const float* lin_w    = (const float*)d_in[6];
  const float* lin_b    = (const float*)d_in[7];
  const float* loop_w   = (const float*)d_in[8];
  const float* evolve_w = (const float*)d_in[9];
  float* out = (float*)d_out;

  const int N = in_sizes[1];   // norm is [N]
  const int E = in_sizes[2];   // edge_src is [E]  (1.6M, divisible by 4)
  const int E4 = E >> 2;

  // workspace: s1[N] | s2[N] | offs[N] | partials[256] | ebuf[E] uint2
  float* s1       = (float*)d_ws;
  float* s2       = s1 + N;
  int*   offs     = (int*)(s2 + N);
  int*   partials = offs + N;
  uint2* ebuf     = (uint2*)(partials + SCAN_BLOCKS);

  const int ipb = (N + SCAN_BLOCKS - 1) / SCAN_BLOCKS;  // 196 for N=50000

  precompute_att<<<512, 256, 0, stream>>>(feat, lin_w, lin_b, s1, s2, offs, N);
  hist_dst<<<(E4 + 255) / 256, 256, 0, stream>>>((const int4*)edst, offs, E4);
  scan_partials<<<SCAN_BLOCKS, SCAN_TPB, 0, stream>>>(offs, partials, N, ipb);
  scan_level2<<<1, SCAN_BLOCKS, 0, stream>>>(partials);
  scan_chunks<<<SCAN_BLOCKS, SCAN_TPB, 0, stream>>>(offs, partials, N, ipb);
  scatter_att<<<(E4 + 255) / 256, 256, 0, stream>>>((const int4*)esrc,
                                                    (const int4*)edst,
                                                    s1, s2, offs, ebuf, E4);
  const int rblocks = (N + NPW * 4 - 1) / (NPW * 4);   // 1563 for N=50000
  reduce_finalize<<<rblocks, 256, 0, stream>>>(feat, norm, offs, ebuf,
                                               W_rel, loop_w, evolve_w, out, N);
}